// Round 16
// 951.590 us; speedup vs baseline: 4.2339x; 1.0597x over previous
//
#include <hip/hip_runtime.h>

// ======================= types & helpers =======================
using u16 = unsigned short;
typedef short bf16x8 __attribute__((ext_vector_type(8)));
typedef float f32x4  __attribute__((ext_vector_type(4)));

__device__ __forceinline__ float bf2f(u16 u) { return __uint_as_float(((unsigned)u) << 16); }
__device__ __forceinline__ u16 f2bf(float f) {  // round-to-nearest-even
  unsigned u = __float_as_uint(f);
  return (u16)((u + 0x7FFFu + ((u >> 16) & 1u)) >> 16);
}
__device__ __forceinline__ float ldv(const float* p) { return *p; }
__device__ __forceinline__ float ldv(const u16* p)   { return bf2f(*p); }
__device__ __forceinline__ void  stv(float* p, float v) { *p = v; }
__device__ __forceinline__ void  stv(u16* p, float v)   { *p = f2bf(v); }

// ======================= problem constants =======================
constexpr int cB = 4, cT = 12, cN = 2048, cF = 26;
constexpr int cHID = 128, cLF = 32, cFF = 256, cHOR = 12;
constexpr int cE = 16384;
constexpr int cR = cB * cT * cN;   // 98304
constexpr int cBT = cB * cT;       // 48
constexpr float cALPHA = 0.9f, cBETA = 0.8f, cEPS = 1e-5f;

#define FLAG_ACC  1
#define FLAG_BIAS 2
#define FLAG_RELU 4
#define FLAG_NE   8   // epilogue += ne16[(gm % cN)*cHID + gn] (encoder node_emb)

// ======================= MFMA bf16 GEMM (gload_lds + dbuf + XCD swizzle) ==========
// C[m,n] = sum_k A[m,k] * BT[n,k]  (+bias) (+C) (+node_emb) (relu)
// A: bf16 [M,K] lda ; BT: bf16 [N,K] ldbt. M%(WM*128)==0, K%32==0, lda/ldbt%8==0;
// N guarded (OOB B rows clamp to N-1; their output columns never stored).
// WM: tile = (WM*128) x (NF*32), WM*4 waves. biasPerT: bias[cT][N], row (m0/2048)%cT.
template <int WM, int NF, typename TC>
__global__ __launch_bounds__(WM * 256)
void gemm_mfma(const u16* __restrict__ A, const u16* __restrict__ BT,
               TC* __restrict__ C, const float* __restrict__ bias,
               int M, int N, int K, int lda, int ldbt, int ldc,
               long batchA, long batchB, long batchC, int flags, int biasPerT,
               const u16* __restrict__ ne16)
{
  constexpr int TN = NF * 32;
  constexpr int AROWS = WM * 128;
  constexpr int ROWS = AROWS + TN;      // A rows then BT rows
  constexpr int NINST = ROWS / 16;      // gload_lds wave-instrs per K-step
  constexpr int WAVES = WM * 4;
  constexpr int NPW = (NINST + WAVES - 1) / WAVES;
  __shared__ __align__(16) u16 S[2][ROWS * 32];

  // bijective XCD-aware block remap
  const long gx = gridDim.x, gy = gridDim.y;
  const long total = gx * gy * (long)gridDim.z;
  long lid = blockIdx.x + gx * (blockIdx.y + gy * (long)blockIdx.z);
  { const long q = total >> 3, r = total & 7, xcd = lid & 7, j = lid >> 3;
    lid = (xcd < r ? xcd * (q + 1) : r * (q + 1) + (xcd - r) * q) + j; }
  const int bz = (int)(lid / (gx * gy));
  const long rem = lid % (gx * gy);
  const int by = (int)(rem / gx), bx = (int)(rem % gx);

  A  += (long)bz * batchA;
  BT += (long)bz * batchB;
  C  += (long)bz * batchC;
  const int tid = threadIdx.x;
  const int lane = tid & 63, wid = tid >> 6;
  const int wm = wid & (2 * WM - 1);
  const int wn = wid >> WM;
  const int m0 = bx * AROWS, n0 = by * TN;
  const int fr = lane & 15, kh = lane >> 4;   // frag row / k-half
  const int nwi = (NINST - wid + WAVES - 1) / WAVES;

  // hoisted per-lane staging pointers (advance +32 elts per K-step)
  const u16* gp[NPW];
#pragma unroll
  for (int i = 0; i < NPW; ++i) {
    const int s = wid + i * WAVES;
    if (s < NINST) {
      const int slot = s * 64 + lane;    // linear 16B LDS slot
      const int row = slot >> 2, q = slot & 3;
      if (row < AROWS) {
        gp[i] = A + (long)(m0 + row) * lda + q * 8;
      } else {
        const int n = min(n0 + row - AROWS, N - 1);
        gp[i] = BT + (long)n * ldbt + q * 8;
      }
    } else {
      gp[i] = A;
    }
  }

  f32x4 acc[4][NF];
#pragma unroll
  for (int i = 0; i < 4; ++i)
#pragma unroll
    for (int j = 0; j < NF; ++j) acc[i][j] = f32x4{0.f, 0.f, 0.f, 0.f};

  auto STAGE = [&](int buf) {
#pragma unroll
    for (int i = 0; i < NPW; ++i) {
      if (i < nwi) {
        const int s = wid + i * WAVES;
        __builtin_amdgcn_global_load_lds(
            (const __attribute__((address_space(1))) unsigned int*)gp[i],
            (__attribute__((address_space(3))) unsigned int*)&S[buf][s * 512],
            16, 0, 0);
        gp[i] += 32;
      }
    }
  };

  STAGE(0);
  int cur = 0;
  for (int k0 = 0; k0 < K; k0 += 32) {
    __syncthreads();                 // drains vmcnt -> S[cur] ready; prior reads of S[cur^1] done
    if (k0 + 32 < K) STAGE(cur ^ 1);
    bf16x8 af[4];
#pragma unroll
    for (int mf = 0; mf < 4; ++mf)
      af[mf] = *(const bf16x8*)&S[cur][(wm * 64 + mf * 16 + fr) * 32 + kh * 8];
#pragma unroll
    for (int nf = 0; nf < NF; ++nf) {
      const bf16x8 bfr =
          *(const bf16x8*)&S[cur][(AROWS + wn * NF * 16 + nf * 16 + fr) * 32 + kh * 8];
#pragma unroll
      for (int mf = 0; mf < 4; ++mf)
        acc[mf][nf] = __builtin_amdgcn_mfma_f32_16x16x32_bf16(af[mf], bfr, acc[mf][nf], 0, 0, 0);
    }
    cur ^= 1;
  }

  const float* bp = bias;
  if (biasPerT && bias) bp = bias + (long)((m0 >> 11) % cT) * N;

#pragma unroll
  for (int mf = 0; mf < 4; ++mf)
#pragma unroll
    for (int nf = 0; nf < NF; ++nf) {
      const int gn = n0 + wn * NF * 16 + nf * 16 + fr;
      if (gn < N) {
#pragma unroll
        for (int r = 0; r < 4; ++r) {
          const long gm = m0 + wm * 64 + mf * 16 + kh * 4 + r;   // C/D: row=(lane>>4)*4+r
          float v = acc[mf][nf][r];
          if (flags & FLAG_BIAS) v += bp[gn];
          if (flags & FLAG_NE)   v += bf2f(ne16[(long)((int)(gm & (cN - 1))) * cHID + gn]);
          if (flags & FLAG_ACC)  v += ldv(&C[gm * ldc + gn]);
          if (flags & FLAG_RELU) v = fmaxf(v, 0.f);
          stv(&C[gm * ldc + gn], v);
        }
      }
    }
}

// ======================= small f32 matmul: C[M,N] = A[M,K] @ B[K,N] ==========
__global__ __launch_bounds__(256)
void matmul_small(const float* __restrict__ A, const float* __restrict__ B,
                  float* __restrict__ C, int M, int N, int K)
{
  const int idx = blockIdx.x * 256 + threadIdx.x;
  if (idx >= M * N) return;
  const int m = idx / N, n = idx % N;
  float acc = 0.f;
  for (int k = 0; k < K; ++k) acc = fmaf(A[m * K + k], B[k * N + n], acc);
  C[idx] = acc;
}

// ======================= LIF composed coefficients ==========
__device__ __forceinline__ void lif_coeffs(float* k1, float* k2, float* k3)
{
  float ap = 1.f;
  for (int m = 0; m < cT; ++m) {
    k1[m] = (m ? cBETA * k1[m - 1] : 0.f) + ap;   // k1[m] = sum a^i b^(m-i)
    ap *= cALPHA;
  }
  for (int m = 0; m < cT; ++m) { float s = 0.f; for (int i = 0; i <= m; ++i) s += k1[i] * k1[m - i]; k2[m] = s; }
  for (int m = 0; m < cT; ++m) { float s = 0.f; for (int i = 0; i <= m; ++i) s += k2[i] * k1[m - i]; k3[m] = s; }
}

// Btot[t][ch] = C3[t]*(b1@W23)[ch] + C2[t]*(b2@W3)[ch] + C1[t]*b3[ch]; Ci = cumsum(ki)
__global__ void btot_full(const float* __restrict__ b1, const float* __restrict__ b2,
                          const float* __restrict__ b3, const float* __restrict__ W23,
                          const float* __restrict__ W3, float* __restrict__ Btot, int c)
{
  const int ch = threadIdx.x;
  if (ch >= c) return;
  float k1[cT], k2[cT], k3[cT]; lif_coeffs(k1, k2, k3);
  float v1 = 0.f, v2 = 0.f;
  for (int j = 0; j < c; ++j) { v1 = fmaf(b1[j], W23[j * c + ch], v1); v2 = fmaf(b2[j], W3[j * c + ch], v2); }
  float C1 = 0.f, C2 = 0.f, C3 = 0.f;
  for (int t = 0; t < cT; ++t) {
    C1 += k1[t]; C2 += k2[t]; C3 += k3[t];
    Btot[t * c + ch] = C3 * v1 + C2 * v2 + C1 * b3[ch];
  }
}

// last-t-only variant -> out[c]
__global__ void btot_last(const float* __restrict__ b1, const float* __restrict__ b2,
                          const float* __restrict__ b3, const float* __restrict__ W23,
                          const float* __restrict__ W3, float* __restrict__ out, int c)
{
  const int ch = threadIdx.x;
  if (ch >= c) return;
  float k1[cT], k2[cT], k3[cT]; lif_coeffs(k1, k2, k3);
  float v1 = 0.f, v2 = 0.f;
  for (int j = 0; j < c; ++j) { v1 = fmaf(b1[j], W23[j * c + ch], v1); v2 = fmaf(b2[j], W3[j * c + ch], v2); }
  float C1 = 0.f, C2 = 0.f, C3 = 0.f;
  for (int t = 0; t < cT; ++t) { C1 += k1[t]; C2 += k2[t]; C3 += k3[t]; }
  out[ch] = C3 * v1 + C2 * v2 + C1 * b3[ch];
}

// bias1p[n] = skb1[n] + sum_k Btot11[k] * skw1[k][n]
__global__ void bias_sk(const float* __restrict__ Btot11, const float* __restrict__ skw1,
                        const float* __restrict__ skb1, float* __restrict__ out)
{
  const int n = threadIdx.x;
  float acc = skb1[n];
  for (int k = 0; k < 192; ++k) acc = fmaf(Btot11[k], skw1[k * 256 + n], acc);
  out[n] = acc;
}

__global__ void vadd2(const float* __restrict__ a, const float* __restrict__ b,
                      float* __restrict__ o, int n)
{
  const int i = threadIdx.x;
  if (i < n) o[i] = a[i] + b[i];
}

// ======================= 3x cascaded LIF (= S^3), full sequence out ==========
__global__ __launch_bounds__(256)
void cascade3_full(const u16* __restrict__ in, u16* __restrict__ out, int c)
{
  const int c8 = c >> 3;
  const long total = (long)cB * cN * c8;
  const long idx = (long)blockIdx.x * 256 + threadIdx.x;
  if (idx >= total) return;
  const long nc = (long)cN * c;
  const int b = (int)(idx / ((long)cN * c8));
  const long rest = (idx % ((long)cN * c8)) * 8;
  const u16* p = in  + (long)b * cT * nc + rest;
  u16*       q = out + (long)b * cT * nc + rest;
  float s1[8] = {}, m1[8] = {}, s2[8] = {}, m2[8] = {}, s3[8] = {}, m3[8] = {};
#pragma unroll
  for (int t = 0; t < cT; ++t) {
    const bf16x8 v = *(const bf16x8*)&p[(long)t * nc];
    u16 o[8];
#pragma unroll
    for (int e = 0; e < 8; ++e) {
      s1[e] = fmaf(cALPHA, s1[e], bf2f((u16)v[e])); m1[e] = fmaf(cBETA, m1[e], s1[e]);
      s2[e] = fmaf(cALPHA, s2[e], m1[e]);           m2[e] = fmaf(cBETA, m2[e], s2[e]);
      s3[e] = fmaf(cALPHA, s3[e], m2[e]);           m3[e] = fmaf(cBETA, m3[e], s3[e]);
      o[e] = f2bf(m3[e]);
    }
    *(bf16x8*)&q[(long)t * nc] = *(const bf16x8*)o;
  }
}

// same, but store only the t=T-1 slice into out [cB*cN, c]
__global__ __launch_bounds__(256)
void cascade3_last(const u16* __restrict__ in, u16* __restrict__ out, int c)
{
  const int c8 = c >> 3;
  const long total = (long)cB * cN * c8;
  const long idx = (long)blockIdx.x * 256 + threadIdx.x;
  if (idx >= total) return;
  const long nc = (long)cN * c;
  const int b = (int)(idx / ((long)cN * c8));
  const long rest = (idx % ((long)cN * c8)) * 8;
  const u16* p = in + (long)b * cT * nc + rest;
  float s1[8] = {}, m1[8] = {}, s2[8] = {}, m2[8] = {}, s3[8] = {}, m3[8] = {};
#pragma unroll
  for (int t = 0; t < cT; ++t) {
    const bf16x8 v = *(const bf16x8*)&p[(long)t * nc];
#pragma unroll
    for (int e = 0; e < 8; ++e) {
      s1[e] = fmaf(cALPHA, s1[e], bf2f((u16)v[e])); m1[e] = fmaf(cBETA, m1[e], s1[e]);
      s2[e] = fmaf(cALPHA, s2[e], m1[e]);           m2[e] = fmaf(cBETA, m2[e], s2[e]);
      s3[e] = fmaf(cALPHA, s3[e], m2[e]);           m3[e] = fmaf(cBETA, m3[e], s3[e]);
    }
  }
  u16 o[8];
#pragma unroll
  for (int e = 0; e < 8; ++e) o[e] = f2bf(m3[e]);
  *(bf16x8*)&out[(long)b * nc + rest] = *(const bf16x8*)o;
}

// ======================= weight convert + transpose (f32 [K,N] -> bf16 [N,K]) ==========
__global__ __launch_bounds__(256)
void wconvT(const float* __restrict__ w, u16* __restrict__ wt, int K, int N)
{
  const long idx = (long)blockIdx.x * 256 + threadIdx.x;
  if (idx >= (long)K * N) return;
  const int n = (int)(idx / K), k = (int)(idx % K);
  wt[idx] = f2bf(w[(long)k * N + n]);
}

// pack diffconv+denseconv weights: W1/W2 [160][480] bf16
__global__ __launch_bounds__(256)
void wpack_dcds(const float* __restrict__ dcw, const float* __restrict__ dsw,
                u16* __restrict__ W1, u16* __restrict__ W2)
{
  const int idx = blockIdx.x * 256 + threadIdx.x;
  if (idx >= 2 * 160 * 480) return;
  const int which = idx / (160 * 480);
  const int l = idx % (160 * 480);
  const int n = l / 480, k = l % 480;
  float v;
  if (k < 320) v = dcw[(long)(which * 320 + k) * 160 + n];
  else         v = dsw[(long)(which * 160 + (k - 320)) * 160 + n];
  (which ? W2 : W1)[l] = f2bf(v);
}

// 3 independent transposes fused (skw0 160x256, rw1 256x512, rw2 512x312)
__global__ __launch_bounds__(256)
void wconv_multi(const float* __restrict__ w2, u16* __restrict__ d2,
                 const float* __restrict__ w3, u16* __restrict__ d3,
                 const float* __restrict__ w4, u16* __restrict__ d4)
{
  const long s2 = 160L * 256, s3 = s2 + 256L * 512, s4 = s3 + 512L * 312;
  long idx = (long)blockIdx.x * 256 + threadIdx.x;
  const float* w; u16* d; int K, N; long base;
  if      (idx < s2) { w = w2; d = d2; K = 160; N = 256; base = 0;  }
  else if (idx < s3) { w = w3; d = d3; K = 256; N = 512; base = s2; }
  else if (idx < s4) { w = w4; d = d4; K = 512; N = 312; base = s3; }
  else return;
  const long l = idx - base;
  const int n = (int)(l / K), k = (int)(l % K);
  d[l] = f2bf(w[(long)k * N + n]);
}

// encoder GEMM prep: Xp [cR][32] bf16 (K pad 26->32), wencT [128][32] bf16, ne16 bf16
__global__ __launch_bounds__(256)
void enc_prep(const float* __restrict__ x, const float* __restrict__ enc_w,
              const float* __restrict__ ne,
              u16* __restrict__ Xp, u16* __restrict__ wencT, u16* __restrict__ ne16)
{
  const long sX = (long)cR * 32, sW = sX + 128 * 32, sN = sW + (long)cN * cHID;
  const long idx = (long)blockIdx.x * 256 + threadIdx.x;
  if (idx < sX) {
    const long row = idx >> 5; const int f = (int)(idx & 31);
    Xp[idx] = (f < cF) ? f2bf(x[row * cF + f]) : (u16)0;
  } else if (idx < sW) {
    const long l = idx - sX; const int n = (int)(l >> 5), k = (int)(l & 31);
    wencT[l] = (k < cF) ? f2bf(enc_w[(long)k * cHID + n]) : (u16)0;
  } else if (idx < sN) {
    const long l = idx - sW;
    ne16[l] = f2bf(ne[l]);
  }
}

// fill H0 cols [128,160) with lw0 (bf16x8 stores)
__global__ __launch_bounds__(256)
void lw_fill(const float* __restrict__ lw, u16* __restrict__ h)
{
  const long idx = (long)blockIdx.x * 256 + threadIdx.x;   // over cR*4
  if (idx >= (long)cR * 4) return;
  const long row = idx >> 2; const int g = (int)(idx & 3) * 8;
  const int n = (int)(row & (cN - 1));
  const f32x4 a = *(const f32x4*)&lw[(long)n * cLF + g];
  const f32x4 b = *(const f32x4*)&lw[(long)n * cLF + g + 4];
  u16 o[8];
#pragma unroll
  for (int q = 0; q < 8; ++q) o[q] = f2bf(q < 4 ? a[q] : b[q - 4]);
  *(bf16x8*)&h[row * 160 + cHID + g] = *(const bf16x8*)o;
}

// ======================= tiled bf16 transpose: in [R,Cc] ld ldi -> out [Cc,R], batched ====
__global__ __launch_bounds__(256)
void transpose_bf16(const u16* __restrict__ in, int ldi, u16* __restrict__ out,
                    int R, int Cc, long batchIn, long batchOut)
{
  __shared__ u16 t[64][65];
  in  += (long)blockIdx.z * batchIn;
  out += (long)blockIdx.z * batchOut;
  const int tid = threadIdx.x;
  const int r0 = blockIdx.x * 64, c0 = blockIdx.y * 64;
  for (int i = tid; i < 64 * 64; i += 256) {
    const int r = i >> 6, c = i & 63;
    t[r][c] = (r0 + r < R && c0 + c < Cc) ? in[(long)(r0 + r) * ldi + c0 + c] : (u16)0;
  }
  __syncthreads();
  for (int i = tid; i < 64 * 64; i += 256) {
    const int c = i >> 6, r = i & 63;
    if (c0 + c < Cc && r0 + r < R) out[(long)(c0 + c) * R + r0 + r] = t[r][c];
  }
}

// convert src_emb and tgt_emb in one dispatch
__global__ __launch_bounds__(256)
void cvt2_f2bf(const float* __restrict__ a, u16* __restrict__ oa,
               const float* __restrict__ b, u16* __restrict__ ob, long n)
{
  const long idx = (long)blockIdx.x * 256 + threadIdx.x;
  if (idx < n) oa[idx] = f2bf(a[idx]);
  else if (idx < 2 * n) ob[idx - n] = f2bf(b[idx - n]);
}

// ======================= graph preprocessing (CSR build) =======================
__global__ __launch_bounds__(256)
void edge_stats(const int* __restrict__ s, const int* __restrict__ d,
                const float* __restrict__ ew, float* degf, float* degb,
                int* cntf, int* cntb)
{
  const int e = blockIdx.x * 256 + threadIdx.x;
  atomicAdd(&degf[d[e]], ew[e]);
  atomicAdd(&degb[s[e]], ew[e]);
  atomicAdd(&cntf[d[e]], 1);
  atomicAdd(&cntb[s[e]], 1);
}

__global__ __launch_bounds__(256)
void scan2(const int* __restrict__ cf, const int* __restrict__ cb,
           int* __restrict__ rf, int* __restrict__ rb)
{
  const int* c = blockIdx.x ? cb : cf;
  int* r       = blockIdx.x ? rb : rf;
  __shared__ int part[256];
  const int t = threadIdx.x, base = t * 8;
  int loc[8]; int s = 0;
#pragma unroll
  for (int i = 0; i < 8; ++i) { loc[i] = c[base + i]; s += loc[i]; }
  part[t] = s; __syncthreads();
  if (t == 0) {
    int run = 0;
    for (int i = 0; i < 256; ++i) { const int v = part[i]; part[i] = run; run += v; }
    r[2048] = run;
  }
  __syncthreads();
  int run = part[t];
#pragma unroll
  for (int i = 0; i < 8; ++i) { r[base + i] = run; run += loc[i]; }
}

__global__ __launch_bounds__(256)
void fill_csr(const int* __restrict__ s, const int* __restrict__ d,
              const float* __restrict__ ew,
              const float* __restrict__ degf, const float* __restrict__ degb,
              const int* __restrict__ rowf, const int* __restrict__ rowb,
              int* curf, int* curb,
              int* __restrict__ colf, int* __restrict__ colb,
              float* __restrict__ wnf, float* __restrict__ wnb)
{
  const int e = blockIdx.x * 256 + threadIdx.x;
  const int si = s[e], di = d[e];
  const float w = ew[e];
  const int p = rowf[di] + atomicAdd(&curf[di], 1);
  colf[p] = si; wnf[p] = w / fmaxf(degf[di], 1e-6f);
  const int q = rowb[si] + atomicAdd(&curb[si], 1);
  colb[q] = di; wnb[q] = w / fmaxf(degb[si], 1e-6f);
}

// ======================= diffusion step, L2-sliced: one bt per block ==========
constexpr int cNPB = 12;                       // nodes per block
constexpr int cNCH = (cN + cNPB - 1) / cNPB;   // 171 chunks
__global__ __launch_bounds__(256)
void prop_gather_bt(const u16* __restrict__ x, int ldx, u16* __restrict__ y, int ldy,
                    const int* __restrict__ rowptr, const int* __restrict__ col,
                    const float* __restrict__ w)
{
  const int lid = blockIdx.x;                  // 0 .. 8*6*cNCH-1
  const int xcd = lid & 7, j = lid >> 3;
  const int bt = xcd * 6 + (j % 6);            // 6 bt per XCD
  const int chunk = j / 6;
  const int item = threadIdx.x;                // (node_i, ch8)
  if (item >= cNPB * 20) return;
  const int n = chunk * cNPB + item / 20;
  if (n >= cN) return;
  const int ch = (item % 20) * 8;
  const int beg = rowptr[n], end = rowptr[n + 1];
  const u16* xb = x + (long)bt * cN * ldx + ch;
  float acc[8] = {};
  int jj = beg;
  for (; jj + 1 < end; jj += 2) {
    const int c0 = col[jj], c1 = col[jj + 1];
    const float w0 = w[jj], w1 = w[jj + 1];
    const bf16x8 v0 = *(const bf16x8*)&xb[(long)c0 * ldx];
    const bf16x8 v1 = *(const bf16x8*)&xb[(long)c1 * ldx];
#pragma unroll
    for (int q = 0; q < 8; ++q) {
      acc[q] = fmaf(w0, bf2f((u16)v0[q]), acc[q]);
      acc[q] = fmaf(w1, bf2f((u16)v1[q]), acc[q]);
    }
  }
  if (jj < end) {
    const float w0 = w[jj];
    const bf16x8 v0 = *(const bf16x8*)&xb[(long)col[jj] * ldx];
#pragma unroll
    for (int q = 0; q < 8; ++q) acc[q] = fmaf(w0, bf2f((u16)v0[q]), acc[q]);
  }
  u16 o[8];
#pragma unroll
  for (int q = 0; q < 8; ++q) o[q] = f2bf(acc[q]);
  *(bf16x8*)&y[((long)bt * cN + n) * ldy + ch] = *(const bf16x8*)o;
}

// ======================= adjacency: row softmax of relu(scores) ==========
__global__ __launch_bounds__(256)
void relu_softmax_rows(const float* __restrict__ sc, u16* __restrict__ adj)
{
  const int row = blockIdx.x, tid = threadIdx.x;
  const float* p = sc + (long)row * cN;
  __shared__ float red[256];
  float lv[8];
  float mx = 0.f;   // relu => all >= 0
#pragma unroll
  for (int i = 0; i < 8; ++i) {
    const float v = fmaxf(p[tid + i * 256], 0.f);
    lv[i] = v; mx = fmaxf(mx, v);
  }
  red[tid] = mx; __syncthreads();
  for (int s = 128; s > 0; s >>= 1) { if (tid < s) red[tid] = fmaxf(red[tid], red[tid + s]); __syncthreads(); }
  const float m = red[0]; __syncthreads();
  float sum = 0.f;
#pragma unroll
  for (int i = 0; i < 8; ++i) { lv[i] = __expf(lv[i] - m); sum += lv[i]; }
  red[tid] = sum; __syncthreads();
  for (int s = 128; s > 0; s >>= 1) { if (tid < s) red[tid] += red[tid + s]; __syncthreads(); }
  const float inv = 1.f / red[0]; __syncthreads();
#pragma unroll
  for (int i = 0; i < 8; ++i) adj[(long)row * cN + tid + i * 256] = f2bf(lv[i] * inv);
}

// ======================= batch norm (bf16 inputs) =======================
__global__ __launch_bounds__(256)
void bn_stats(const u16* __restrict__ d, const u16* __restrict__ res,
              float* __restrict__ stat, int c)
{
  const int ch = threadIdx.x;
  const long r0 = (long)blockIdx.x * (cR / 512);
  float s = 0.f, s2 = 0.f;
  for (int i = 0; i < cR / 512; ++i) {
    const float v = bf2f(d[(r0 + i) * c + ch]) + bf2f(res[(r0 + i) * c + ch]);
    s += v; s2 = fmaf(v, v, s2);
  }
  atomicAdd(&stat[ch], s);
  atomicAdd(&stat[c + ch], s2);
}

__global__ __launch_bounds__(256)
void bn_finalize(const float* __restrict__ stat, const float* __restrict__ g,
                 const float* __restrict__ b, float* __restrict__ scsh, int c)
{
  const int ch = threadIdx.x;
  const float mu = stat[ch] / cR;
  const float var = stat[c + ch] / cR - mu * mu;
  const float sc = g[ch] * rsqrtf(var + cEPS);
  scsh[ch] = sc;
  scsh[c + ch] = fmaf(-mu, sc, b[ch]);
}

__global__ __launch_bounds__(192)
void bn_apply_concat(const u16* __restrict__ d, const u16* __restrict__ res,
                     const float* __restrict__ scsh, const float* __restrict__ lw,
                     u16* __restrict__ out)
{
  const int tid = threadIdx.x;
  const long r0 = (long)blockIdx.x * 8;
  for (long row = r0; row < r0 + 8; ++row) {
    const int n = (int)(row % cN);
    float v;
    if (tid < 160) v = fmaf(bf2f(d[row * 160 + tid]) + bf2f(res[row * 160 + tid]),
                            scsh[tid], scsh[160 + tid]);
    else           v = lw[(long)n * cLF + (tid - 160)];
    out[row * 192 + tid] = f2bf(v);
  }
}

// ======================= output transpose (bf16 in, f32 out) =======================
__global__ __launch_bounds__(256)
void final_transpose(const u16* __restrict__ y, float* __restrict__ out)
{
  const long idx = (long)blockIdx.x * 256 + threadIdx.x;
  const int f = (int)(idx % cF);
  long t = idx / cF;
  const int n = (int)(t % cN); t /= cN;
  const int hor = (int)(t % cHOR);
  const int b = (int)(t / cHOR);
  out[idx] = bf2f(y[((long)b * cN + n) * (cHOR * cF) + hor * cF + f]);
}

__global__ __launch_bounds__(256)
void fill_f32(float* __restrict__ out, long n, float val)
{
  const long idx = (long)blockIdx.x * 256 + threadIdx.x;
  if (idx < n) out[idx] = val;
}

// ======================= host orchestration =======================
extern "C" void kernel_launch(void* const* d_in, const int* in_sizes, int n_in,
                              void* d_out, int out_size, void* d_ws, size_t ws_size,
                              hipStream_t stream)
{
  float* outF = (float*)d_out;
  const long outN = out_size;
  if (n_in < 34) { fill_f32<<<(int)((outN + 255) / 256), 256, 0, stream>>>(outF, outN, 500.f); return; }
  if (in_sizes[0] != cB * cT * cN * cF || in_sizes[1] != 2 * cE || in_sizes[9] != 3 * 160 * 160) {
    fill_f32<<<(int)((outN + 255) / 256), 256, 0, stream>>>(outF, outN, 700.f); return;
  }

  const float* x        = (const float*)d_in[0];
  const int*   eidx     = (const int*)d_in[1];
  const float* ew       = (const float*)d_in[2];
  const float* enc_w    = (const float*)d_in[3];
  const float* enc_b    = (const float*)d_in[4];
  const float* node_emb = (const float*)d_in[5];
  const float* src_emb  = (const float*)d_in[6];
  const float* tgt_emb  = (const float*)d_in[7];
  const float* lw0  = (const float*)d_in[8];
  const float* tW0  = (const float*)d_in[9];
  const float* tb0  = (const float*)d_in[10];
  const float* dcw0 = (const float*)d_in[11];
  const float* dcb0 = (const float*)d_in[12];
  const float* dsw0 = (const float*)d_in[13];
  const float* dsb0 = (const float*)d_in[14];
  const float* skw0 = (const float*)d_in[15];
  const float* skb0 = (const float*)d_in[16];
  const float* ng0  = (const float*)d_in[17];
  const float* nb0  = (const float*)d_in[18];
  const float* lw1  = (const float*)d_in[19];
  const float* tW1  = (const float*)d_in[20];
  const float* tb1  = (const float*)d_in[21];
  // d_in[22..25, 28..29] feed only block-1's post-skip h (never read) -> dead.
  const float* skw1 = (const float*)d_in[26];
  const float* skb1 = (const float*)d_in[27];
  const float* rw1  = (const float*)d_in[30];
  const float* rb1  = (const float*)d_in[31];
  const float* rw2  = (const float*)d_in[32];
  const float* rb2  = (const float*)d_in[33];
  const int* srcI = eidx;
  const int* dstI = eidx + cE;

  // ---- workspace layout ----
  char* W = (char*)d_ws;
  size_t off = 0;
  auto A8 = [&](size_t bytes) { size_t r = off; off = (off + bytes + 255) & ~(size_t)255; return r; };
  const size_t oH0 = A8((size_t)cR * 160 * 2);   // res, bf16
  const size_t oHh = A8((size_t)cR * 160 * 2);   // chain h; G1 [cR,192] = Hh + PK head
  const size_t oPK = A8((size_t)cR * 480 * 2);   // pack [z|z|x], 94.5 MB (scores/r1/yb alias)
  const size_t oSx = A8((size_t)cR * 160 * 2);   // Xp -> cascade out -> hT -> x1T -> block1 last
  const size_t oDd = A8((size_t)cR * 160 * 2);   // bf16 accumulator
  const size_t oAdj = A8((size_t)cN * cN * 2);
  const size_t oOut = A8((size_t)cB * cN * cFF * 2);       // bf16 skip acc (t=11)
  const size_t oZero = A8(6 * 2048 * 4 + 2 * 192 * 4);
  const size_t oRowf = A8(2049 * 4), oRowb = A8(2049 * 4);
  const size_t oColf = A8((size_t)cE * 4), oColb = A8((size_t)cE * 4);
  const size_t oWnf  = A8((size_t)cE * 4), oWnb  = A8((size_t)cE * 4);
  const size_t oScSh = A8(2 * 192 * 4);
  const size_t oWT   = A8((size_t)900000 * 2);   // bf16 weights (+ wencT + ne16)
  const size_t oSeb  = A8((size_t)cN * cHID * 2);
  const size_t oTeb  = A8((size_t)cN * cHID * 2);
  const size_t oW23  = A8(192 * 192 * 4);
  const size_t oW123 = A8(192 * 192 * 4);
  const size_t oWskp = A8(192 * 256 * 4);
  const size_t oBt0  = A8(cT * 160 * 4);
  const size_t oBt11 = A8(192 * 4);
  const size_t oBsk1 = A8(256 * 4);
  const size_t oBsum = A8(160 * 4);
  if (off > ws_size) {
    fill_f32<<<(int)((outN + 255) / 256), 256, 0, stream>>>(outF, outN, 300.f);
    return;
  }

  u16 *H0 = (u16*)(W + oH0), *Hh = (u16*)(W + oHh), *PK = (u16*)(W + oPK),
      *Sx = (u16*)(W + oSx), *Dd = (u16*)(W + oDd), *adjb = (u16*)(W + oAdj);
  u16 *G1 = Hh;                          // [cR,192] over Hh + PK head (post-BN only)
  u16 *Xp = Sx;                          // encoder GEMM input alias (dead before cascade)
  float* scores = (float*)PK;            // phase-0 alias (16.8 MB)
  u16 *r1b = PK + 16L * 1024 * 1024;     // readout alias (PK dead then)
  u16 *ybB = PK + 28L * 1024 * 1024;
  u16 *outB = (u16*)(W + oOut);
  float* zero = (float*)(W + oZero);
  float *degf = zero, *degb = zero + 2048;
  int *cntf = (int*)(zero + 4096), *cntb = cntf + 2048,
      *curf = cntb + 2048, *curb = curf + 2048;
  float* stat = (float*)(curb + 2048);
  int *rowf = (int*)(W + oRowf), *rowb = (int*)(W + oRowb);
  int *colf = (int*)(W + oColf), *colb = (int*)(W + oColb);
  float *wnf = (float*)(W + oWnf), *wnb = (float*)(W + oWnb);
  float* scsh = (float*)(W + oScSh);
  u16* wt = (u16*)(W + oWT);
  u16 *wt123_0 = wt,               *wsk1pT = wt123_0 + 25600,
      *W1pk = wsk1pT + 49152,      *W2pk = W1pk + 76800,
      *wsk0 = W2pk + 76800,        *wr1 = wsk0 + 40960,
      *wr2 = wr1 + 131072,         *wencT = wr2 + 159744,
      *ne16 = wencT + 4096;        // ends 830464 < 900000
  u16 *seb = (u16*)(W + oSeb), *teb = (u16*)(W + oTeb);
  float *W23 = (float*)(W + oW23), *W123 = (float*)(W + oW123), *Wskp = (float*)(W + oWskp);
  float *Bt0 = (float*)(W + oBt0), *Bt11 = (float*)(W + oBt11), *Bsk1 = (float*)(W + oBsk1);
  float *Bsum = (float*)(W + oBsum);

  // big-M GEMMs: WM=2 (256-row tile, 512 threads)
  auto g5u = [&](const u16* Aq, const u16* Bq, u16* Cq, const float* bias,
                 int M, int N, int K, int lda, int ldbt, int ldc,
                 long bA, long bB, long bC, int batch, int flags, int bpt = 0) {
    dim3 g(M / 256, (N + 159) / 160, batch);
    gemm_mfma<2, 5, u16><<<g, 512, 0, stream>>>(Aq, Bq, Cq, bias, M, N, K, lda, ldbt, ldc, bA, bB, bC, flags, bpt, nullptr);
  };
  // small-M GEMMs: WM=1 (128-row tile, 256 threads)
  auto g4f = [&](const u16* Aq, const u16* Bq, float* Cq, const float* bias,
                 int M, int N, int K, int lda, int ldbt, int ldc,
                 long bA, long bB, long bC, int batch, int flags) {
    dim3 g(M / 128, (N + 127) / 128, batch);
    gemm_mfma<1, 4, float><<<g, 256, 0, stream>>>(Aq, Bq, Cq, bias, M, N, K, lda, ldbt, ldc, bA, bB, bC, flags, 0, nullptr);
  };
  auto g4u = [&](const u16* Aq, const u16* Bq, u16* Cq, const float* bias,
                 int M, int N, int K, int lda, int ldbt, int ldc,
                 long bA, long bB, long bC, int batch, int flags) {
    dim3 g(M / 128, (N + 127) / 128, batch);
    gemm_mfma<1, 4, u16><<<g, 256, 0, stream>>>(Aq, Bq, Cq, bias, M, N, K, lda, ldbt, ldc, bA, bB, bC, flags, 0, nullptr);
  };
  auto wcv = [&](const float* src, u16* dst, int K, int N) {
    wconvT<<<(int)(((long)K * N + 255) / 256), 256, 0, stream>>>(src, dst, K, N);
  };
  auto mms = [&](const float* Aq, const float* Bq, float* Cq, int M, int N, int K) {
    matmul_small<<<(M * N + 255) / 256, 256, 0, stream>>>(Aq, Bq, Cq, M, N, K);
  };

  // ---- phase 0a: composed chain weights ----
  mms(tW0 + 1L * 25600, tW0 + 2L * 25600, W23, 160, 160, 160);
  mms(tW0,              W23,              W123, 160, 160, 160);
  wcv(W123, wt123_0, 160, 160);
  btot_full<<<1, 160, 0, stream>>>(tb0, tb0 + 160, tb0 + 320, W23, tW0 + 2L * 25600, Bt0, 160);
  mms(tW1 + 1L * 36864, tW1 + 2L * 36864, W23, 192, 192, 192);
  mms(tW1,              W23,              W123, 192, 192, 192);
  mms(W123, skw1, Wskp, 192, 256, 192);
  wcv(Wskp, wsk1pT, 192, 256);
  btot_last<<<1, 192, 0, stream>>>(tb1, tb1 + 192, tb1 + 384, W23, tW1 + 2L * 36864, Bt11, 192);
  bias_sk<<<1, 256, 0, stream>>>(Bt11, skw1, skb1, Bsk1);
  vadd2<<<1, 160, 0, stream>>>(dcb0, dsb0, Bsum, 160);

  // ---- phase 0b: weight packs, CSR, encoder(GEMM), adjacency ----
  wpack_dcds<<<(2 * 160 * 480 + 255) / 256, 256, 0, stream>>>(dcw0, dsw0, W1pk, W2pk);
  {
    const long tot = 160L * 256 + 256L * 512 + 512L * 312;
    wconv_multi<<<(int)((tot + 255) / 256), 256, 0, stream>>>(skw0, wsk0, rw1, wr1, rw2, wr2);
  }
  hipMemsetAsync(zero, 0, 6 * 2048 * 4 + 2 * 192 * 4, stream);
  edge_stats<<<cE / 256, 256, 0, stream>>>(srcI, dstI, ew, degf, degb, cntf, cntb);
  scan2<<<2, 256, 0, stream>>>(cntf, cntb, rowf, rowb);
  fill_csr<<<cE / 256, 256, 0, stream>>>(srcI, dstI, ew, degf, degb, rowf, rowb,
                                         curf, curb, colf, colb, wnf, wnb);

  // encoder = MFMA GEMM: H0[:, :128] = Xp @ enc_wT + enc_b + node_emb; [:,128:160] = lw0
  {
    const long tot = (long)cR * 32 + 128 * 32 + (long)cN * cHID;
    enc_prep<<<(int)((tot + 255) / 256), 256, 0, stream>>>(x, enc_w, node_emb, Xp, wencT, ne16);
    lw_fill<<<(int)(((long)cR * 4 + 255) / 256), 256, 0, stream>>>(lw0, H0);
    dim3 g(cR / 256, 1, 1);
    gemm_mfma<2, 4, u16><<<g, 512, 0, stream>>>(Xp, wencT, H0, enc_b,
        cR, cHID, 32, 32, 32, 160, 0, 0, 0, FLAG_BIAS | FLAG_NE, 0, ne16);
  }

  cvt2_f2bf<<<(2 * cN * cHID + 255) / 256, 256, 0, stream>>>(src_emb, seb, tgt_emb, teb, (long)cN * cHID);
  g4f(seb, teb, scores, nullptr, cN, cN, cHID, cHID, cHID, cN, 0, 0, 0, 1, 0);
  relu_softmax_rows<<<cN, 256, 0, stream>>>(scores, adjb);

  const int PROP_GRID = 8 * 6 * cNCH;

  // ---- block 0 (c = 160) ----
  {
    const int c = 160;
    const long NC = (long)cN * c;
    const long PB = (long)cN * 480;      // per-bt pack stride
    const int casGrid = (int)(((long)cB * cN * (c / 8) + 255) / 256);
    // chain: Sx = S^3 H0 ; Hh = Sx @ W123_0 + Bt0[t]   (Sx overwrites Xp, now dead)
    cascade3_full<<<casGrid, 256, 0, stream>>>(H0, Sx, c);
    g5u(Sx, wt123_0, Hh, Bt0, cR, c, c, c, c, c, 0, 0, 0, 1, FLAG_BIAS, /*bpt=*/1);
    // skip (t=11) -> bf16 outB
    g4u(Hh + 11L * NC, wsk0, outB, skb0, cN, cFF, c, c, c, cFF,
        (long)cT * NC, 0, (long)cN * cFF, cB, FLAG_BIAS);
    // hT -> Sx
    dim3 tg(cN / 64, (c + 63) / 64, cBT);
    transpose_bf16<<<tg, 256, 0, stream>>>(Hh, c, Sx, cN, c, NC, NC);
    // pack1 = [z1 | z2 | x1]
    prop_gather_bt<<<PROP_GRID, 256, 0, stream>>>(Hh, 160, PK, 480, rowf, colf, wnf);
    prop_gather_bt<<<PROP_GRID, 256, 0, stream>>>(PK, 480, PK + 160, 480, rowf, colf, wnf);
    g5u(adjb, Sx, PK + 320, nullptr, cN, c, cN, cN, cN, 480, 0, NC, PB, cBT, 0);   // x1
    // GEMM1: Dd = pack1 @ W1 + (dcb0+dsb0)
    g5u(PK, W1pk, Dd, Bsum, cR, c, 480, 480, 480, c, 0, 0, 0, 1, FLAG_BIAS);
    // x1T -> Sx (hT dead)
    transpose_bf16<<<tg, 256, 0, stream>>>(PK + 320, 480, Sx, cN, c, PB, NC);
    // pack2 = [z3 | z4 | x2]
    prop_gather_bt<<<PROP_GRID, 256, 0, stream>>>(Hh, 160, PK, 480, rowb, colb, wnb);
    prop_gather_bt<<<PROP_GRID, 256, 0, stream>>>(PK, 480, PK + 160, 480, rowb, colb, wnb);
    g5u(adjb, Sx, PK + 320, nullptr, cN, c, cN, cN, cN, 480, 0, NC, PB, cBT, 0);   // x2
    // GEMM2: Dd += pack2 @ W2
    g5u(PK, W2pk, Dd, nullptr, cR, c, 480, 480, 480, c, 0, 0, 0, 1, FLAG_ACC);
    // BN(Dd + H0) -> G1 (stride 192) + lw1
    bn_stats<<<512, c, 0, stream>>>(Dd, H0, stat, c);
    bn_finalize<<<1, c, 0, stream>>>(stat, ng0, nb0, scsh, c);
    bn_apply_concat<<<cR / 8, 192, 0, stream>>>(Dd, H0, scsh, lw1, G1);
  }

  // ---- block 1 (c = 192): composed chain+skip, only t=11 survives ----
  {
    const int c = 192;
    const int casGrid = (int)(((long)cB * cN * (c / 8) + 255) / 256);
    cascade3_last<<<casGrid, 256, 0, stream>>>(G1, Sx, c);
    g4u(Sx, wsk1pT, outB, Bsk1, cB * cN, cFF, c, c, c, cFF,
        0, 0, 0, 1, FLAG_BIAS | FLAG_ACC | FLAG_RELU);
  }

  // ---- readout (all bf16) ----
  g4u(outB, wr1, r1b, rb1, cB * cN, 2 * cFF, cFF, cFF, cFF, 2 * cFF,
      0, 0, 0, 1, FLAG_BIAS | FLAG_RELU);
  g4u(r1b, wr2, ybB, rb2, cB * cN, cHOR * cF, 2 * cFF, 2 * cFF, 2 * cFF, cHOR * cF,
      0, 0, 0, 1, FLAG_BIAS);
  final_transpose<<<(cB * cHOR * cN * cF) / 256, 256, 0, stream>>>(ybB, outF);
}